// Round 7
// baseline (387.899 us; speedup 1.0000x reference)
//
#include <hip/hip_runtime.h>

// Chamfer forward: dist0[i] = min_j ||pc0[i]-pc1[j]||^2 ; out = mean(dist0[dist0<=2])
// N = M = 65536, fp32. VALU-bound brute force.
// m_j = 0.5||c_j||^2 - p.c_j (half-norm in LDS .w); d = max(2*min_m + ||p||^2, 0).
// Points packed in pairs (v2f) -> v_pk_fma_f32 (2 fp32 FMA/lane/cyc).
// KEY (round 7): TILE=2048 -> 32 KB LDS/block. The RA's VGPR budget comes from the
// LDS-derived occupancy cap (160K/32K = 5 blocks/CU -> 5 waves/EU -> ~102 VGPRs).
// At 16 KB LDS the heuristic targeted 8 waves/EU = 64 VGPRs and chunked/spilled the
// inner loop (rounds 4-6, all flat ~350 us, R6 FETCH jumped 2.5x = scratch).

typedef float v2f __attribute__((ext_vector_type(2)));
typedef float v4f __attribute__((ext_vector_type(4)));

constexpr int TILE  = 2048;   // candidates per LDS tile (16 B each = 32 KB)
constexpr int BLOCK = 256;
constexpr int P     = 16;     // points per thread
constexpr int PP    = P / 2;  // packed point pairs
constexpr int S     = 32;     // candidate slices (grid.y); 512 blocks = 2/CU

static __device__ __forceinline__ v2f pk_fma(v2f a, v2f b, v2f c) {
  return __builtin_elementwise_fma(a, b, c);   // -> v_pk_fma_f32 (verified R5)
}

static __device__ __forceinline__ float halfnorm(float x, float y, float z) {
  return 0.5f * fmaf(x, x, fmaf(y, y, z * z));
}

__global__ __launch_bounds__(BLOCK, 4)
void nn_min_kernel(const float* __restrict__ pc0, const float* __restrict__ pc1,
                   unsigned int* __restrict__ bests /* [n0] fp32 bits */) {
  __shared__ v4f s[TILE];   // 32 KB: sets the occupancy cap the RA budgets for

  const int t = threadIdx.x;
  const int pointBase = blockIdx.x * (BLOCK * P);
  const int c0i       = blockIdx.y * TILE;

  // stage TILE candidates: 8/thread via 6 coalesced 16B loads; .w = 0.5*||c||^2
  {
    const int cbase = 8 * t;
    const v4f* g = (const v4f*)(pc1 + (size_t)3 * (c0i + cbase));
    const v4f a = g[0], b = g[1], c = g[2], d = g[3], e = g[4], f = g[5];
    s[cbase + 0] = (v4f){a.x, a.y, a.z, halfnorm(a.x, a.y, a.z)};
    s[cbase + 1] = (v4f){a.w, b.x, b.y, halfnorm(a.w, b.x, b.y)};
    s[cbase + 2] = (v4f){b.z, b.w, c.x, halfnorm(b.z, b.w, c.x)};
    s[cbase + 3] = (v4f){c.y, c.z, c.w, halfnorm(c.y, c.z, c.w)};
    s[cbase + 4] = (v4f){d.x, d.y, d.z, halfnorm(d.x, d.y, d.z)};
    s[cbase + 5] = (v4f){d.w, e.x, e.y, halfnorm(d.w, e.x, e.y)};
    s[cbase + 6] = (v4f){e.z, e.w, f.x, halfnorm(e.z, e.w, f.x)};
    s[cbase + 7] = (v4f){f.y, f.z, f.w, halfnorm(f.y, f.z, f.w)};
  }

  // P points, negated, packed as pairs (p=2*pp and p=2*pp+1)
  v2f nx2[PP], ny2[PP], nz2[PP], best2[PP];
#pragma unroll
  for (int pp = 0; pp < PP; ++pp) {
    const int i0 = pointBase + (2 * pp) * BLOCK + t;   // coalesced per slot
    const int i1 = i0 + BLOCK;
    nx2[pp] = (v2f){-pc0[3 * i0 + 0], -pc0[3 * i1 + 0]};
    ny2[pp] = (v2f){-pc0[3 * i0 + 1], -pc0[3 * i1 + 1]};
    nz2[pp] = (v2f){-pc0[3 * i0 + 2], -pc0[3 * i1 + 2]};
    best2[pp] = (v2f){3.4e38f, 3.4e38f};
  }
  __syncthreads();

#pragma unroll 4
  for (int k = 0; k < TILE; k += 2) {
    const v4f ca = s[k];      // wave-uniform addr -> broadcast, conflict-free
    const v4f cb = s[k + 1];
    // splat candidate fields once per iter, reused across all PP pairs
    const v2f cax = {ca.x, ca.x}, cay = {ca.y, ca.y},
              caz = {ca.z, ca.z}, caw = {ca.w, ca.w};
    const v2f cbx = {cb.x, cb.x}, cby = {cb.y, cb.y},
              cbz = {cb.z, cb.z}, cbw = {cb.w, cb.w};
#pragma unroll
    for (int pp = 0; pp < PP; ++pp) {
      const v2f m0 = pk_fma(nx2[pp], cax, pk_fma(ny2[pp], cay, pk_fma(nz2[pp], caz, caw)));
      const v2f m1 = pk_fma(nx2[pp], cbx, pk_fma(ny2[pp], cby, pk_fma(nz2[pp], cbz, cbw)));
      best2[pp].x = fminf(best2[pp].x, fminf(m0.x, m1.x));  // -> v_min3_f32
      best2[pp].y = fminf(best2[pp].y, fminf(m0.y, m1.y));
    }
  }

  // d = max(2m + ||p||^2, 0) >= 0 -> bitwise atomicMin is order-preserving
#pragma unroll
  for (int pp = 0; pp < PP; ++pp) {
    const float pn0 = fmaf(nx2[pp].x, nx2[pp].x,
                      fmaf(ny2[pp].x, ny2[pp].x, nz2[pp].x * nz2[pp].x));
    const float pn1 = fmaf(nx2[pp].y, nx2[pp].y,
                      fmaf(ny2[pp].y, ny2[pp].y, nz2[pp].y * nz2[pp].y));
    const int i0 = pointBase + (2 * pp) * BLOCK + t;
    const int i1 = i0 + BLOCK;
    const float d0 = fmaxf(fmaf(2.0f, best2[pp].x, pn0), 0.0f);
    const float d1 = fmaxf(fmaf(2.0f, best2[pp].y, pn1), 0.0f);
    atomicMin(&bests[i0], __float_as_uint(d0));
    atomicMin(&bests[i1], __float_as_uint(d1));
  }
}

__global__ __launch_bounds__(BLOCK) void reduce_kernel(
    const unsigned int* __restrict__ bests, int n0,
    float* __restrict__ accum /* [0]=sum, [1]=count */) {
  const int per = n0 / (gridDim.x * BLOCK);   // elements per thread
  float v = 0.f, c = 0.f;
  for (int j = 0; j < per; ++j) {
    const int i = blockIdx.x * (BLOCK * per) + j * BLOCK + threadIdx.x;
    const float d = __uint_as_float(bests[i]);
    if (d <= 2.0f) { v += d; c += 1.0f; }
  }
  for (int off = 32; off > 0; off >>= 1) {
    v += __shfl_down(v, off, 64);
    c += __shfl_down(c, off, 64);
  }
  __shared__ float wsum[BLOCK / 64], wcnt[BLOCK / 64];
  const int wid = threadIdx.x >> 6;
  if ((threadIdx.x & 63) == 0) { wsum[wid] = v; wcnt[wid] = c; }
  __syncthreads();
  if (threadIdx.x == 0) {
    float sS = 0.f, cS = 0.f;
    for (int w = 0; w < BLOCK / 64; ++w) { sS += wsum[w]; cS += wcnt[w]; }
    atomicAdd(&accum[0], sS);
    atomicAdd(&accum[1], cS);
  }
}

__global__ void finalize_kernel(const float* __restrict__ accum,
                                float* __restrict__ out) {
  out[0] = accum[0] / accum[1];
}

extern "C" void kernel_launch(void* const* d_in, const int* in_sizes, int n_in,
                              void* d_out, int out_size, void* d_ws, size_t ws_size,
                              hipStream_t stream) {
  const float* pc0 = (const float*)d_in[0];
  const float* pc1 = (const float*)d_in[1];
  float* out = (float*)d_out;

  const int n0 = in_sizes[0] / 3;   // 65536
  const int n1 = in_sizes[1] / 3;   // 65536
  (void)n1;

  unsigned int* bests = (unsigned int*)d_ws;              // n0 * 4 bytes
  float* accum = (float*)((char*)d_ws + (size_t)n0 * 4);  // 2 floats

  // init: bests = 0x7F7F7F7F (~3.39e38, > any distance), accum = 0
  hipMemsetAsync(bests, 0x7F, (size_t)n0 * 4, stream);
  hipMemsetAsync(accum, 0, 2 * sizeof(float), stream);

  dim3 grid(n0 / (BLOCK * P), S);   // 16 x 32 = 512 blocks = 2/CU
  nn_min_kernel<<<grid, BLOCK, 0, stream>>>(pc0, pc1, bests);
  reduce_kernel<<<64, BLOCK, 0, stream>>>(bests, n0, accum);
  finalize_kernel<<<1, 1, 0, stream>>>(accum, out);
}

// Round 8
// 363.001 us; speedup vs baseline: 1.0686x; 1.0686x over previous
//
#include <hip/hip_runtime.h>

// Chamfer forward: dist0[i] = min_j ||pc0[i]-pc1[j]||^2 ; out = mean(dist0[dist0<=2])
// N = M = 65536, fp32. VALU-bound brute force.
// m_j = 0.5||c_j||^2 - p.c_j (half-norm in LDS .w); d = max(2*min_m + ||p||^2, 0).
// ROUND 8: full inline-asm inner loop with FIXED registers. Rounds 4-7 proved the
// scheduler always restructures (chunks/spills) to hit 8 waves/EU = 64 VGPRs,
// re-reading LDS and costing 2x the VALU floor. Here:
//   v96-v103  : candidate pair (2x ds_read_b128 dest)        [clobbered]
//   v104-v107 : m0/m1 temporaries                            [clobbered]
//   v108-v123 : 16 running minima, persist across iterations [clobbered]
//   points    : asm operands (compiler-allocated, forced live by the asm)
// op_sel/op_sel_hi on v_pk_fma_f32 broadcasts candidate fields straight from the
// ds_read pair -> zero splat movs. 68 instr / 2048 point-candidates per iter.

typedef float v2f __attribute__((ext_vector_type(2)));
typedef float v4f __attribute__((ext_vector_type(4)));

constexpr int TILE  = 1024;   // candidates per LDS tile (16 B each = 16 KB)
constexpr int BLOCK = 256;
constexpr int P     = 16;     // points per thread
constexpr int PP    = P / 2;  // packed point pairs
constexpr int S     = 64;     // candidate slices; 1024 blocks = 4/CU

static __device__ __forceinline__ float halfnorm(float x, float y, float z) {
  return 0.5f * fmaf(x, x, fmaf(y, y, z * z));
}

// One point-pair vs candidate pair (ca in v[96:99], cb in v[100:103]).
// m = nz*z_bc + w_bc ; m = ny*y_bc + m ; m = nx*x_bc + m ; best = min3(best, m0, m1)
#define PPQ(NX, NY, NZ, BL, BH)                                                                         \
  "v_pk_fma_f32 v[104:105], %[" NZ "], v[98:99], v[98:99] op_sel:[0,0,1] op_sel_hi:[1,0,1]\n\t"         \
  "v_pk_fma_f32 v[106:107], %[" NZ "], v[102:103], v[102:103] op_sel:[0,0,1] op_sel_hi:[1,0,1]\n\t"     \
  "v_pk_fma_f32 v[104:105], %[" NY "], v[96:97], v[104:105] op_sel:[0,1,0] op_sel_hi:[1,1,1]\n\t"       \
  "v_pk_fma_f32 v[106:107], %[" NY "], v[100:101], v[106:107] op_sel:[0,1,0] op_sel_hi:[1,1,1]\n\t"     \
  "v_pk_fma_f32 v[104:105], %[" NX "], v[96:97], v[104:105] op_sel:[0,0,0] op_sel_hi:[1,0,1]\n\t"       \
  "v_pk_fma_f32 v[106:107], %[" NX "], v[100:101], v[106:107] op_sel:[0,0,0] op_sel_hi:[1,0,1]\n\t"     \
  "v_min3_f32 " BL ", " BL ", v104, v106\n\t"                                                           \
  "v_min3_f32 " BH ", " BH ", v105, v107\n\t"

#define CLOBBERS                                                              \
  "v96","v97","v98","v99","v100","v101","v102","v103","v104","v105","v106",   \
  "v107","v108","v109","v110","v111","v112","v113","v114","v115","v116",      \
  "v117","v118","v119","v120","v121","v122","v123"

__global__ __launch_bounds__(BLOCK, 4)
void nn_min_kernel(const float* __restrict__ pc0, const float* __restrict__ pc1,
                   unsigned int* __restrict__ bests /* [n0] fp32 bits */) {
  __shared__ v4f s[TILE];

  const int t = threadIdx.x;
  const int pointBase = blockIdx.x * (BLOCK * P);
  const int c0i       = blockIdx.y * TILE;

  // stage TILE candidates: 4/thread via 3 coalesced 16B loads; .w = 0.5*||c||^2
  {
    const int cbase = 4 * t;
    const v4f* g = (const v4f*)(pc1 + (size_t)3 * (c0i + cbase));
    const v4f a = g[0], b = g[1], c = g[2];
    s[cbase + 0] = (v4f){a.x, a.y, a.z, halfnorm(a.x, a.y, a.z)};
    s[cbase + 1] = (v4f){a.w, b.x, b.y, halfnorm(a.w, b.x, b.y)};
    s[cbase + 2] = (v4f){b.z, b.w, c.x, halfnorm(b.z, b.w, c.x)};
    s[cbase + 3] = (v4f){c.y, c.z, c.w, halfnorm(c.y, c.z, c.w)};
  }

  // P points, negated, packed as pairs (lo = point 2*pp, hi = point 2*pp+1)
  v2f nx2[PP], ny2[PP], nz2[PP];
#pragma unroll
  for (int pp = 0; pp < PP; ++pp) {
    const int i0 = pointBase + (2 * pp) * BLOCK + t;   // coalesced per slot
    const int i1 = i0 + BLOCK;
    nx2[pp] = (v2f){-pc0[3 * i0 + 0], -pc0[3 * i1 + 0]};
    ny2[pp] = (v2f){-pc0[3 * i0 + 1], -pc0[3 * i1 + 1]};
    nz2[pp] = (v2f){-pc0[3 * i0 + 2], -pc0[3 * i1 + 2]};
  }

  // init running minima v108..v123 = +huge (0x7e967699 ~ 1e38)
  asm volatile(
      "v_mov_b32 v108, 0x7e967699\n\t" "v_mov_b32 v109, 0x7e967699\n\t"
      "v_mov_b32 v110, 0x7e967699\n\t" "v_mov_b32 v111, 0x7e967699\n\t"
      "v_mov_b32 v112, 0x7e967699\n\t" "v_mov_b32 v113, 0x7e967699\n\t"
      "v_mov_b32 v114, 0x7e967699\n\t" "v_mov_b32 v115, 0x7e967699\n\t"
      "v_mov_b32 v116, 0x7e967699\n\t" "v_mov_b32 v117, 0x7e967699\n\t"
      "v_mov_b32 v118, 0x7e967699\n\t" "v_mov_b32 v119, 0x7e967699\n\t"
      "v_mov_b32 v120, 0x7e967699\n\t" "v_mov_b32 v121, 0x7e967699\n\t"
      "v_mov_b32 v122, 0x7e967699\n\t" "v_mov_b32 v123, 0x7e967699"
      ::: CLOBBERS);

  __syncthreads();

  unsigned addr = (unsigned)(size_t)&s[0];   // LDS byte offset
#pragma unroll 1
  for (int k = 0; k < TILE; k += 2) {
    asm volatile(
        "ds_read_b128 v[96:99], %[ad]\n\t"
        "ds_read_b128 v[100:103], %[ad] offset:16\n\t"
        "s_waitcnt lgkmcnt(0)\n\t"
        PPQ("nx0", "ny0", "nz0", "v108", "v109")
        PPQ("nx1", "ny1", "nz1", "v110", "v111")
        PPQ("nx2", "ny2", "nz2", "v112", "v113")
        PPQ("nx3", "ny3", "nz3", "v114", "v115")
        PPQ("nx4", "ny4", "nz4", "v116", "v117")
        PPQ("nx5", "ny5", "nz5", "v118", "v119")
        PPQ("nx6", "ny6", "nz6", "v120", "v121")
        PPQ("nx7", "ny7", "nz7", "v122", "v123")
        "v_add_u32 %[ad], 32, %[ad]"
        : [ad] "+v"(addr)
        : [nx0] "v"(nx2[0]), [ny0] "v"(ny2[0]), [nz0] "v"(nz2[0]),
          [nx1] "v"(nx2[1]), [ny1] "v"(ny2[1]), [nz1] "v"(nz2[1]),
          [nx2] "v"(nx2[2]), [ny2] "v"(ny2[2]), [nz2] "v"(nz2[2]),
          [nx3] "v"(nx2[3]), [ny3] "v"(ny2[3]), [nz3] "v"(nz2[3]),
          [nx4] "v"(nx2[4]), [ny4] "v"(ny2[4]), [nz4] "v"(nz2[4]),
          [nx5] "v"(nx2[5]), [ny5] "v"(ny2[5]), [nz5] "v"(nz2[5]),
          [nx6] "v"(nx2[6]), [ny6] "v"(ny2[6]), [nz6] "v"(nz2[6]),
          [nx7] "v"(nx2[7]), [ny7] "v"(ny2[7]), [nz7] "v"(nz2[7])
        : CLOBBERS, "memory");
  }

  // read the 16 minima back out of the fixed registers
  float b[P];
  asm volatile(
      "v_mov_b32 %0, v108\n\t"  "v_mov_b32 %1, v109\n\t"
      "v_mov_b32 %2, v110\n\t"  "v_mov_b32 %3, v111\n\t"
      "v_mov_b32 %4, v112\n\t"  "v_mov_b32 %5, v113\n\t"
      "v_mov_b32 %6, v114\n\t"  "v_mov_b32 %7, v115\n\t"
      "v_mov_b32 %8, v116\n\t"  "v_mov_b32 %9, v117\n\t"
      "v_mov_b32 %10, v118\n\t" "v_mov_b32 %11, v119\n\t"
      "v_mov_b32 %12, v120\n\t" "v_mov_b32 %13, v121\n\t"
      "v_mov_b32 %14, v122\n\t" "v_mov_b32 %15, v123"
      : "=v"(b[0]), "=v"(b[1]), "=v"(b[2]), "=v"(b[3]),
        "=v"(b[4]), "=v"(b[5]), "=v"(b[6]), "=v"(b[7]),
        "=v"(b[8]), "=v"(b[9]), "=v"(b[10]), "=v"(b[11]),
        "=v"(b[12]), "=v"(b[13]), "=v"(b[14]), "=v"(b[15])
      :
      : CLOBBERS);

  // d = max(2m + ||p||^2, 0) >= 0 -> bitwise atomicMin is order-preserving
#pragma unroll
  for (int pp = 0; pp < PP; ++pp) {
    const float pn0 = fmaf(nx2[pp].x, nx2[pp].x,
                      fmaf(ny2[pp].x, ny2[pp].x, nz2[pp].x * nz2[pp].x));
    const float pn1 = fmaf(nx2[pp].y, nx2[pp].y,
                      fmaf(ny2[pp].y, ny2[pp].y, nz2[pp].y * nz2[pp].y));
    const int i0 = pointBase + (2 * pp) * BLOCK + t;
    const int i1 = i0 + BLOCK;
    const float d0 = fmaxf(fmaf(2.0f, b[2 * pp + 0], pn0), 0.0f);
    const float d1 = fmaxf(fmaf(2.0f, b[2 * pp + 1], pn1), 0.0f);
    atomicMin(&bests[i0], __float_as_uint(d0));
    atomicMin(&bests[i1], __float_as_uint(d1));
  }
}

__global__ __launch_bounds__(BLOCK) void reduce_kernel(
    const unsigned int* __restrict__ bests, int n0,
    float* __restrict__ accum /* [0]=sum, [1]=count */) {
  const int per = n0 / (gridDim.x * BLOCK);   // elements per thread
  float v = 0.f, c = 0.f;
  for (int j = 0; j < per; ++j) {
    const int i = blockIdx.x * (BLOCK * per) + j * BLOCK + threadIdx.x;
    const float d = __uint_as_float(bests[i]);
    if (d <= 2.0f) { v += d; c += 1.0f; }
  }
  for (int off = 32; off > 0; off >>= 1) {
    v += __shfl_down(v, off, 64);
    c += __shfl_down(c, off, 64);
  }
  __shared__ float wsum[BLOCK / 64], wcnt[BLOCK / 64];
  const int wid = threadIdx.x >> 6;
  if ((threadIdx.x & 63) == 0) { wsum[wid] = v; wcnt[wid] = c; }
  __syncthreads();
  if (threadIdx.x == 0) {
    float sS = 0.f, cS = 0.f;
    for (int w = 0; w < BLOCK / 64; ++w) { sS += wsum[w]; cS += wcnt[w]; }
    atomicAdd(&accum[0], sS);
    atomicAdd(&accum[1], cS);
  }
}

__global__ void finalize_kernel(const float* __restrict__ accum,
                                float* __restrict__ out) {
  out[0] = accum[0] / accum[1];
}

extern "C" void kernel_launch(void* const* d_in, const int* in_sizes, int n_in,
                              void* d_out, int out_size, void* d_ws, size_t ws_size,
                              hipStream_t stream) {
  const float* pc0 = (const float*)d_in[0];
  const float* pc1 = (const float*)d_in[1];
  float* out = (float*)d_out;

  const int n0 = in_sizes[0] / 3;   // 65536
  const int n1 = in_sizes[1] / 3;   // 65536
  (void)n1;

  unsigned int* bests = (unsigned int*)d_ws;              // n0 * 4 bytes
  float* accum = (float*)((char*)d_ws + (size_t)n0 * 4);  // 2 floats

  // init: bests = 0x7F7F7F7F (~3.39e38, > any distance), accum = 0
  hipMemsetAsync(bests, 0x7F, (size_t)n0 * 4, stream);
  hipMemsetAsync(accum, 0, 2 * sizeof(float), stream);

  dim3 grid(n0 / (BLOCK * P), S);   // 16 x 64 = 1024 blocks = 4/CU
  nn_min_kernel<<<grid, BLOCK, 0, stream>>>(pc0, pc1, bests);
  reduce_kernel<<<64, BLOCK, 0, stream>>>(bests, n0, accum);
  finalize_kernel<<<1, 1, 0, stream>>>(accum, out);
}

// Round 9
// 317.237 us; speedup vs baseline: 1.2227x; 1.1443x over previous
//
#include <hip/hip_runtime.h>

// Chamfer forward: dist0[i] = min_j ||pc0[i]-pc1[j]||^2 ; out = mean(dist0[dist0<=2])
// N = M = 65536 i.i.d. N(0,1)^3 points, fp32.
// ROUND 9: spatial grid (counting sort) instead of brute force. R8 proved brute
// force sits at its structural VALU floor (~191 us ideal, ~337 us real; v_pk_fma_f32
// is NOT faster than scalar fma on CDNA4 - fp32 peak 157 TF == scalar rate).
// Grid: 32^3 cells, h=0.25 over [-4,4]^3 (clamped; clamp is a contraction so the
// ring-termination bound stays valid). Both clouds are bucketed; queries are
// processed in sorted order (output is a permutation-invariant sum -> no index
// tracking) so adjacent lanes hit the same cells/candidates. Exact NN: expand
// Chebyshev rings while best > ((r-1)*h)^2. E[candidates] ~ 600/query -> ~4e7
// pairs vs 4.3e9 brute force.

constexpr int   NPTS  = 65536;
constexpr int   GRID  = 32;
constexpr int   NC    = GRID * GRID * GRID;   // 32768 cells
constexpr float H     = 0.25f;
constexpr float ORG   = -4.0f;
constexpr float INVH  = 4.0f;
constexpr int   BLOCK = 256;

__device__ __forceinline__ int cellOf(float x) {
  int c = (int)floorf((x - ORG) * INVH);
  return min(max(c, 0), GRID - 1);
}

__global__ __launch_bounds__(BLOCK) void count_kernel(
    const float* __restrict__ pc0, const float* __restrict__ pc1,
    unsigned* __restrict__ counts0, unsigned* __restrict__ counts1) {
  const int gid = blockIdx.x * BLOCK + threadIdx.x;
  const float* p; unsigned* cnt; int i;
  if (gid < NPTS) { p = pc1; cnt = counts1; i = gid; }
  else            { p = pc0; cnt = counts0; i = gid - NPTS; }
  const float x = p[3 * i], y = p[3 * i + 1], z = p[3 * i + 2];
  const int cid = (cellOf(z) * GRID + cellOf(y)) * GRID + cellOf(x);
  atomicAdd(&cnt[cid], 1u);
}

// One-block exclusive scan of NC elements (1024 threads x 32 each).
__device__ void scan_one(const unsigned* __restrict__ counts,
                         unsigned* __restrict__ starts,
                         unsigned* __restrict__ cursor,
                         unsigned* sc) {
  const int tid = threadIdx.x;
  constexpr int PER = NC / 1024;   // 32
  unsigned loc[PER];
  unsigned run = 0;
  const int base = tid * PER;
  for (int j = 0; j < PER; ++j) { loc[j] = counts[base + j]; run += loc[j]; }
  sc[tid] = run;
  __syncthreads();
  for (int off = 1; off < 1024; off <<= 1) {   // Hillis-Steele inclusive
    unsigned v = 0;
    if (tid >= off) v = sc[tid - off];
    __syncthreads();
    if (tid >= off) sc[tid] += v;
    __syncthreads();
  }
  unsigned r = (tid == 0) ? 0u : sc[tid - 1];  // exclusive
  for (int j = 0; j < PER; ++j) { starts[base + j] = r; cursor[base + j] = r; r += loc[j]; }
  if (tid == 1023) starts[NC] = r;
  __syncthreads();   // protect sc reuse by the next scan
}

__global__ __launch_bounds__(1024) void scan_kernel(
    const unsigned* __restrict__ counts0, unsigned* __restrict__ starts0,
    unsigned* __restrict__ cursor0,
    const unsigned* __restrict__ counts1, unsigned* __restrict__ starts1,
    unsigned* __restrict__ cursor1) {
  __shared__ unsigned sc[1024];
  scan_one(counts1, starts1, cursor1, sc);
  scan_one(counts0, starts0, cursor0, sc);
}

__global__ __launch_bounds__(BLOCK) void scatter_kernel(
    const float* __restrict__ pc0, const float* __restrict__ pc1,
    unsigned* __restrict__ cursor0, unsigned* __restrict__ cursor1,
    float* __restrict__ qx, float* __restrict__ qy, float* __restrict__ qz,
    float* __restrict__ sx, float* __restrict__ sy, float* __restrict__ sz) {
  const int gid = blockIdx.x * BLOCK + threadIdx.x;
  const float* p; unsigned* cur; float *dx, *dy, *dz; int i;
  if (gid < NPTS) { p = pc1; cur = cursor1; dx = sx; dy = sy; dz = sz; i = gid; }
  else            { p = pc0; cur = cursor0; dx = qx; dy = qy; dz = qz; i = gid - NPTS; }
  const float x = p[3 * i], y = p[3 * i + 1], z = p[3 * i + 2];
  const int cid = (cellOf(z) * GRID + cellOf(y)) * GRID + cellOf(x);
  const unsigned pos = atomicAdd(&cur[cid], 1u);
  dx[pos] = x; dy[pos] = y; dz[pos] = z;
}

__global__ __launch_bounds__(BLOCK) void query_kernel(
    const float* __restrict__ qx, const float* __restrict__ qy,
    const float* __restrict__ qz,
    const unsigned* __restrict__ starts,
    const float* __restrict__ sx, const float* __restrict__ sy,
    const float* __restrict__ sz,
    float* __restrict__ accum /* [0]=sum, [1]=count */) {
  const int i = blockIdx.x * BLOCK + threadIdx.x;
  const float px = qx[i], py = qy[i], pz = qz[i];
  const int cx = cellOf(px), cy = cellOf(py), cz = cellOf(pz);
  float best = 3.4e38f;

  auto scanRow = [&](int zz, int yy, int x0, int x1) {
    if (zz < 0 || zz >= GRID || yy < 0 || yy >= GRID) return;
    x0 = max(x0, 0); x1 = min(x1, GRID - 1);
    if (x0 > x1) return;
    const int rb = (zz * GRID + yy) * GRID;
    unsigned j = starts[rb + x0];
    const unsigned e = starts[rb + x1 + 1];   // contiguous row range
    for (; j < e; ++j) {
      const float ddx = px - sx[j];
      const float ddy = py - sy[j];
      const float ddz = pz - sz[j];
      best = fminf(best, fmaf(ddx, ddx, fmaf(ddy, ddy, ddz * ddz)));
    }
  };

  // rings 0+1: 3x3x3 neighborhood as 9 contiguous row scans
  for (int dz = -1; dz <= 1; ++dz)
    for (int dy = -1; dy <= 1; ++dy)
      scanRow(cz + dz, cy + dy, cx - 1, cx + 1);

  // expand: after rings 0..r-1, unsearched points are >= (r-1)*h away
  for (int r = 2; r <= GRID; ++r) {
    const float cov = H * (float)(r - 1);
    if (best <= cov * cov) break;
    for (int dz = -r; dz <= r; ++dz) {
      const int zz = cz + dz;
      if (zz < 0 || zz >= GRID) continue;
      if (dz == -r || dz == r) {
        for (int dy = -r; dy <= r; ++dy)
          scanRow(zz, cy + dy, cx - r, cx + r);
      } else {
        scanRow(zz, cy - r, cx - r, cx + r);
        scanRow(zz, cy + r, cx - r, cx + r);
        for (int dy = -r + 1; dy <= r - 1; ++dy) {
          scanRow(zz, cy + dy, cx - r, cx - r);
          scanRow(zz, cy + dy, cx + r, cx + r);
        }
      }
    }
  }

  // masked mean contribution, block-reduced
  float v = (best <= 2.0f) ? best : 0.0f;
  float c = (best <= 2.0f) ? 1.0f : 0.0f;
  for (int off = 32; off > 0; off >>= 1) {
    v += __shfl_down(v, off, 64);
    c += __shfl_down(c, off, 64);
  }
  __shared__ float wsum[BLOCK / 64], wcnt[BLOCK / 64];
  const int wid = threadIdx.x >> 6;
  if ((threadIdx.x & 63) == 0) { wsum[wid] = v; wcnt[wid] = c; }
  __syncthreads();
  if (threadIdx.x == 0) {
    float sS = 0.f, cS = 0.f;
    for (int w = 0; w < BLOCK / 64; ++w) { sS += wsum[w]; cS += wcnt[w]; }
    atomicAdd(&accum[0], sS);
    atomicAdd(&accum[1], cS);
  }
}

__global__ void finalize_kernel(const float* __restrict__ accum,
                                float* __restrict__ out) {
  out[0] = accum[0] / accum[1];
}

extern "C" void kernel_launch(void* const* d_in, const int* in_sizes, int n_in,
                              void* d_out, int out_size, void* d_ws, size_t ws_size,
                              hipStream_t stream) {
  const float* pc0 = (const float*)d_in[0];
  const float* pc1 = (const float*)d_in[1];
  float* out = (float*)d_out;

  // workspace carve-up (256B-aligned slabs); counts1+counts0 adjacent -> one memset
  char* w = (char*)d_ws;
  auto nxt = [&](size_t bytes) {
    char* p = w; w += (bytes + 255) & ~(size_t)255; return p;
  };
  unsigned* counts1 = (unsigned*)nxt((size_t)NC * 4);
  unsigned* counts0 = (unsigned*)nxt((size_t)NC * 4);
  unsigned* starts1 = (unsigned*)nxt((size_t)(NC + 1) * 4);
  unsigned* cursor1 = (unsigned*)nxt((size_t)NC * 4);
  unsigned* starts0 = (unsigned*)nxt((size_t)(NC + 1) * 4);
  unsigned* cursor0 = (unsigned*)nxt((size_t)NC * 4);
  float* sx = (float*)nxt((size_t)NPTS * 4);
  float* sy = (float*)nxt((size_t)NPTS * 4);
  float* sz = (float*)nxt((size_t)NPTS * 4);
  float* qx = (float*)nxt((size_t)NPTS * 4);
  float* qy = (float*)nxt((size_t)NPTS * 4);
  float* qz = (float*)nxt((size_t)NPTS * 4);
  float* accum = (float*)nxt(8);

  hipMemsetAsync(counts1, 0, (size_t)2 * NC * 4, stream);
  hipMemsetAsync(accum, 0, 8, stream);

  count_kernel<<<2 * NPTS / BLOCK, BLOCK, 0, stream>>>(pc0, pc1, counts0, counts1);
  scan_kernel<<<1, 1024, 0, stream>>>(counts0, starts0, cursor0,
                                      counts1, starts1, cursor1);
  scatter_kernel<<<2 * NPTS / BLOCK, BLOCK, 0, stream>>>(
      pc0, pc1, cursor0, cursor1, qx, qy, qz, sx, sy, sz);
  query_kernel<<<NPTS / BLOCK, BLOCK, 0, stream>>>(qx, qy, qz, starts1,
                                                   sx, sy, sz, accum);
  finalize_kernel<<<1, 1, 0, stream>>>(accum, out);
}

// Round 10
// 259.504 us; speedup vs baseline: 1.4948x; 1.2225x over previous
//
#include <hip/hip_runtime.h>

// Chamfer forward: dist0[i] = min_j ||pc0[i]-pc1[j]||^2 ; out = mean(dist0[dist0<=2])
// N = M = 65536 i.i.d. N(0,1)^3 points, fp32.
// Spatial grid (counting sort), 32^3 cells, h=0.25 over [-4,4]^3 (clamp = contraction,
// ring bound stays valid). Queries sorted too (output is permutation-invariant).
// ROUND 10: query kernel was 8% VALUBusy / 4.3% occupancy (1 wave/SIMD, 3 scalar
// loads/candidate). Now: 4 lanes cooperate per query (grid x4 = 4 waves/SIMD,
// per-lane chains /4), candidates+queries packed float4 (1 dwordx4/candidate,
// 4 sub-lanes load 64B coalesced). Scan rewritten shfl-based (2 barriers vs 20).

constexpr int   NPTS  = 65536;
constexpr int   GRID  = 32;
constexpr int   NC    = GRID * GRID * GRID;   // 32768 cells
constexpr float H     = 0.25f;
constexpr float ORG   = -4.0f;
constexpr float INVH  = 4.0f;
constexpr int   BLOCK = 256;

__device__ __forceinline__ int cellOf(float x) {
  int c = (int)floorf((x - ORG) * INVH);
  return min(max(c, 0), GRID - 1);
}

__global__ __launch_bounds__(BLOCK) void count_kernel(
    const float* __restrict__ pc0, const float* __restrict__ pc1,
    unsigned* __restrict__ counts0, unsigned* __restrict__ counts1) {
  const int gid = blockIdx.x * BLOCK + threadIdx.x;
  const float* p; unsigned* cnt; int i;
  if (gid < NPTS) { p = pc1; cnt = counts1; i = gid; }
  else            { p = pc0; cnt = counts0; i = gid - NPTS; }
  const float x = p[3 * i], y = p[3 * i + 1], z = p[3 * i + 2];
  const int cid = (cellOf(z) * GRID + cellOf(y)) * GRID + cellOf(x);
  atomicAdd(&cnt[cid], 1u);
}

// One-block exclusive scan of NC elements, shfl-based (1024 threads x 32 cells).
__device__ void scan_one(const unsigned* __restrict__ counts,
                         unsigned* __restrict__ starts,
                         unsigned* __restrict__ cursor,
                         unsigned* waveTot /* [16] */) {
  const int tid = threadIdx.x;
  constexpr int PER = NC / 1024;   // 32
  const int base = tid * PER;
  unsigned loc[PER];
  unsigned run = 0;
  for (int j = 0; j < PER; ++j) { loc[j] = counts[base + j]; run += loc[j]; }
  // wave-level inclusive scan of per-thread sums
  unsigned inc = run;
  for (int off = 1; off < 64; off <<= 1) {
    const unsigned v = __shfl_up(inc, off, 64);
    if ((tid & 63) >= off) inc += v;
  }
  if ((tid & 63) == 63) waveTot[tid >> 6] = inc;
  __syncthreads();
  if (tid < 16) {   // scan the 16 wave totals within the first wave
    unsigned w = waveTot[tid];
    for (int off = 1; off < 16; off <<= 1) {
      const unsigned v = __shfl_up(w, off, 16);
      if (tid >= off) w += v;
    }
    waveTot[tid] = w;
  }
  __syncthreads();
  const unsigned waveOff = (tid >> 6) == 0 ? 0u : waveTot[(tid >> 6) - 1];
  unsigned r = waveOff + inc - run;   // exclusive prefix for this thread
  for (int j = 0; j < PER; ++j) { starts[base + j] = r; cursor[base + j] = r; r += loc[j]; }
  if (tid == 1023) starts[NC] = r;
  __syncthreads();   // protect waveTot reuse by the next scan
}

__global__ __launch_bounds__(1024) void scan_kernel(
    const unsigned* __restrict__ counts0, unsigned* __restrict__ starts0,
    unsigned* __restrict__ cursor0,
    const unsigned* __restrict__ counts1, unsigned* __restrict__ starts1,
    unsigned* __restrict__ cursor1) {
  __shared__ unsigned waveTot[16];
  scan_one(counts1, starts1, cursor1, waveTot);
  scan_one(counts0, starts0, cursor0, waveTot);
}

__global__ __launch_bounds__(BLOCK) void scatter_kernel(
    const float* __restrict__ pc0, const float* __restrict__ pc1,
    unsigned* __restrict__ cursor0, unsigned* __restrict__ cursor1,
    float4* __restrict__ q, float4* __restrict__ s) {
  const int gid = blockIdx.x * BLOCK + threadIdx.x;
  const float* p; unsigned* cur; float4* dst; int i;
  if (gid < NPTS) { p = pc1; cur = cursor1; dst = s; i = gid; }
  else            { p = pc0; cur = cursor0; dst = q; i = gid - NPTS; }
  const float x = p[3 * i], y = p[3 * i + 1], z = p[3 * i + 2];
  const int cid = (cellOf(z) * GRID + cellOf(y)) * GRID + cellOf(x);
  const unsigned pos = atomicAdd(&cur[cid], 1u);
  dst[pos] = make_float4(x, y, z, 0.f);
}

// 4 lanes cooperate on one query; lanes stride candidate rows by 4.
__global__ __launch_bounds__(BLOCK) void query_kernel(
    const float4* __restrict__ q,
    const unsigned* __restrict__ starts,
    const float4* __restrict__ s,
    float* __restrict__ accum /* [0]=sum, [1]=count */) {
  const int gtid = blockIdx.x * BLOCK + threadIdx.x;
  const int i   = gtid >> 2;        // query index
  const int sub = gtid & 3;         // sub-lane within the 4-lane group
  const float4 p = q[i];
  const int cx = cellOf(p.x), cy = cellOf(p.y), cz = cellOf(p.z);
  float best = 3.4e38f;

  auto scanRow = [&](int zz, int yy, int x0, int x1) {
    if (zz < 0 || zz >= GRID || yy < 0 || yy >= GRID) return;
    x0 = max(x0, 0); x1 = min(x1, GRID - 1);
    if (x0 > x1) return;
    const int rb = (zz * GRID + yy) * GRID;
    unsigned j = starts[rb + x0] + sub;
    const unsigned e = starts[rb + x1 + 1];   // contiguous row range
    for (; j < e; j += 4) {                   // 4 lanes: 64B coalesced
      const float4 c = s[j];
      const float ddx = p.x - c.x;
      const float ddy = p.y - c.y;
      const float ddz = p.z - c.z;
      best = fminf(best, fmaf(ddx, ddx, fmaf(ddy, ddy, ddz * ddz)));
    }
  };

  // rings 0+1: 3x3x3 neighborhood as 9 contiguous row scans
  for (int dz = -1; dz <= 1; ++dz)
    for (int dy = -1; dy <= 1; ++dy)
      scanRow(cz + dz, cy + dy, cx - 1, cx + 1);

  // combine across the 4 sub-lanes so ring decisions are group-uniform
  best = fminf(best, __shfl_xor(best, 1, 64));
  best = fminf(best, __shfl_xor(best, 2, 64));

  // expand: after rings 0..r-1, unsearched points are >= (r-1)*h away
  for (int r = 2; r <= GRID; ++r) {
    const float cov = H * (float)(r - 1);
    if (best <= cov * cov) break;
    for (int dz = -r; dz <= r; ++dz) {
      const int zz = cz + dz;
      if (zz < 0 || zz >= GRID) continue;
      if (dz == -r || dz == r) {
        for (int dy = -r; dy <= r; ++dy)
          scanRow(zz, cy + dy, cx - r, cx + r);
      } else {
        scanRow(zz, cy - r, cx - r, cx + r);
        scanRow(zz, cy + r, cx - r, cx + r);
        for (int dy = -r + 1; dy <= r - 1; ++dy) {
          scanRow(zz, cy + dy, cx - r, cx - r);
          scanRow(zz, cy + dy, cx + r, cx + r);
        }
      }
    }
    best = fminf(best, __shfl_xor(best, 1, 64));
    best = fminf(best, __shfl_xor(best, 2, 64));
  }

  // masked mean contribution: only sub-lane 0 of each group contributes
  float v = (sub == 0 && best <= 2.0f) ? best : 0.0f;
  float c = (sub == 0 && best <= 2.0f) ? 1.0f : 0.0f;
  for (int off = 32; off > 0; off >>= 1) {
    v += __shfl_down(v, off, 64);
    c += __shfl_down(c, off, 64);
  }
  __shared__ float wsum[BLOCK / 64], wcnt[BLOCK / 64];
  const int wid = threadIdx.x >> 6;
  if ((threadIdx.x & 63) == 0) { wsum[wid] = v; wcnt[wid] = c; }
  __syncthreads();
  if (threadIdx.x == 0) {
    float sS = 0.f, cS = 0.f;
    for (int w = 0; w < BLOCK / 64; ++w) { sS += wsum[w]; cS += wcnt[w]; }
    atomicAdd(&accum[0], sS);
    atomicAdd(&accum[1], cS);
  }
}

__global__ void finalize_kernel(const float* __restrict__ accum,
                                float* __restrict__ out) {
  out[0] = accum[0] / accum[1];
}

extern "C" void kernel_launch(void* const* d_in, const int* in_sizes, int n_in,
                              void* d_out, int out_size, void* d_ws, size_t ws_size,
                              hipStream_t stream) {
  const float* pc0 = (const float*)d_in[0];
  const float* pc1 = (const float*)d_in[1];
  float* out = (float*)d_out;

  // workspace carve-up (256B-aligned slabs); counts1+counts0 adjacent -> one memset
  char* w = (char*)d_ws;
  auto nxt = [&](size_t bytes) {
    char* p = w; w += (bytes + 255) & ~(size_t)255; return p;
  };
  unsigned* counts1 = (unsigned*)nxt((size_t)NC * 4);
  unsigned* counts0 = (unsigned*)nxt((size_t)NC * 4);
  unsigned* starts1 = (unsigned*)nxt((size_t)(NC + 1) * 4);
  unsigned* cursor1 = (unsigned*)nxt((size_t)NC * 4);
  unsigned* starts0 = (unsigned*)nxt((size_t)(NC + 1) * 4);
  unsigned* cursor0 = (unsigned*)nxt((size_t)NC * 4);
  float4* s = (float4*)nxt((size_t)NPTS * 16);
  float4* q = (float4*)nxt((size_t)NPTS * 16);
  float* accum = (float*)nxt(8);

  hipMemsetAsync(counts1, 0, (size_t)2 * NC * 4, stream);
  hipMemsetAsync(accum, 0, 8, stream);

  count_kernel<<<2 * NPTS / BLOCK, BLOCK, 0, stream>>>(pc0, pc1, counts0, counts1);
  scan_kernel<<<1, 1024, 0, stream>>>(counts0, starts0, cursor0,
                                      counts1, starts1, cursor1);
  scatter_kernel<<<2 * NPTS / BLOCK, BLOCK, 0, stream>>>(
      pc0, pc1, cursor0, cursor1, q, s);
  query_kernel<<<4 * NPTS / BLOCK, BLOCK, 0, stream>>>(q, starts1, s, accum);
  finalize_kernel<<<1, 1, 0, stream>>>(accum, out);
}